// Round 11
// baseline (78.745 us; speedup 1.0000x reference)
//
#include <hip/hip_runtime.h>

// KnowledgeConsistentAttention v10 (MI355X / gfx950)
// sumpool3x3(scores)[p,q] = kern[p,:] . G[:,q], G = sumpool3x3(fg)
// => flash attention, K=V=kern (normalized fg cols + eps), Q = G cols, d=64.
//
// v10: v6 block shape (grid 256 = (b,y), 1024 thr = 8 p-groups x 2 q-strips,
// full softmax in-block) with a ZERO-barrier ZERO-LDS main loop: A- and
// B-fragments read straight from L2-resident ws, A double-buffered in named
// register sets (2x unrolled loop), KB loaded at tile top. setprio around
// MFMA clusters. LDS used only by the proven v6 epilogue combine.

typedef __bf16 bf16_t;
typedef __bf16 bf16x2 __attribute__((ext_vector_type(2)));
typedef __bf16 bf16x8 __attribute__((ext_vector_type(8)));
typedef float f32x4 __attribute__((ext_vector_type(4)));

#define HW_ 4096
#define CH 64

static __device__ __forceinline__ int pack_bf16x2(float a, float b) {
  bf16x2 p; p[0] = (bf16_t)a; p[1] = (bf16_t)b;
  return __builtin_bit_cast(int, p);
}

// ---------------- prep: kern (2 layouts) + pooled/prescaled Q ----------------
__global__ __launch_bounds__(1024, 1) void kca_prep(const float* __restrict__ fg,
                                                    char* __restrict__ KpB,
                                                    char* __restrict__ KBB,
                                                    char* __restrict__ GtB) {
  const int b = blockIdx.x >> 6, y = blockIdx.x & 63;
  const int t = threadIdx.x;
  const float* F = fg + (size_t)b * (CH * HW_);

  __shared__ float  Ft[3 * 64 * 64];   // [r][c][x] f32, rows y-1..y+1
  __shared__ bf16_t Ks[64 * 72];       // [x][c], stride 72 (144B, 16B-aligned)
  __shared__ bf16_t Gs[64 * 72];
  __shared__ float  red[16][64];
  __shared__ float  rn[64];

#pragma unroll
  for (int k = 0; k < 3; ++k) {
    const int o = t + k * 1024;          // f32x4 index
    const int r = o >> 10, c = (o >> 4) & 63, x4 = o & 15;
    const int gy = y - 1 + r;
    f32x4 v = {0.f, 0.f, 0.f, 0.f};
    if (gy >= 0 && gy <= 63) v = *(const f32x4*)(F + c * HW_ + gy * 64 + x4 * 4);
    *(f32x4*)&Ft[o * 4] = v;
  }
  __syncthreads();

  const int x = t & 63, c0 = t >> 6;     // c0 in 0..15 -> channels 4*c0..+3
  float v4[4], g4[4], ssq = 0.f;
#pragma unroll
  for (int i = 0; i < 4; ++i) {
    const int c = c0 * 4 + i;
    const float v = Ft[4096 + c * 64 + x] + 1e-7f;
    v4[i] = v; ssq = fmaf(v, v, ssq);
    float s = 0.f;
#pragma unroll
    for (int r = 0; r < 3; ++r) {
      const float* row = &Ft[r * 4096 + c * 64];
      float vv = row[x];
      if (x > 0)  vv += row[x - 1];
      if (x < 63) vv += row[x + 1];
      s += vv;
    }
    g4[i] = s * 1.4426950408889634f;     // log2e prescale (exp2-domain softmax)
  }
  red[c0][x] = ssq;
  __syncthreads();
  if (t < 512) red[t >> 6][t & 63] += red[(t >> 6) + 8][t & 63];
  __syncthreads();
  if (t < 256) red[t >> 6][t & 63] += red[(t >> 6) + 4][t & 63];
  __syncthreads();
  if (t < 64) rn[t] = 1.0f / sqrtf(red[0][t] + red[1][t] + red[2][t] + red[3][t]);
  __syncthreads();
  {
    const float rv = rn[x];
    bf16x2* ksp = (bf16x2*)((char*)Ks + x * 144 + c0 * 8);
    bf16x2* gsp = (bf16x2*)((char*)Gs + x * 144 + c0 * 8);
    bf16x2 k0; k0[0] = (bf16_t)(v4[0] * rv); k0[1] = (bf16_t)(v4[1] * rv);
    bf16x2 k1; k1[0] = (bf16_t)(v4[2] * rv); k1[1] = (bf16_t)(v4[3] * rv);
    bf16x2 g0; g0[0] = (bf16_t)g4[0]; g0[1] = (bf16_t)g4[1];
    bf16x2 g1; g1[0] = (bf16_t)g4[2]; g1[1] = (bf16_t)g4[3];
    ksp[0] = k0; ksp[1] = k1;
    gsp[0] = g0; gsp[1] = g1;
  }
  __syncthreads();

  char* Kp_b = KpB + (size_t)b * (HW_ * CH * 2) + (size_t)y * 8192;  // [p][c] 128B rows
  char* Gt_b = GtB + (size_t)b * (HW_ * CH * 2) + (size_t)y * 8192;  // [q][c] 128B rows
  char* KB_b = KBB + (size_t)b * (HW_ * CH * 2);                     // [tile][mt][lane][16B]
  if (t < 512) {
    const int row = t >> 3, colb = (t & 7) * 16;
    *(bf16x8*)(Kp_b + row * 128 + colb) = *(const bf16x8*)((char*)Ks + row * 144 + colb);
    // KB: GEMM2 B-fragment order with slot permutation baked in.
    // lane(l15,lg) word j = kern[tile*32 + 16*(j>>2) + 4*lg + (j&3)][16*mt + l15]
    const int tile = t >> 8;           // 0..1
    const int mt   = (t >> 6) & 3;
    const int ln   = t & 63;
    const int l15_ = ln & 15, lg_ = ln >> 4;
    bf16x8 kv;
#pragma unroll
    for (int j = 0; j < 8; ++j) {
      const int pl = tile * 32 + 16 * (j >> 2) + 4 * lg_ + (j & 3);
      kv[j] = Ks[pl * 72 + 16 * mt + l15_];
    }
    *(bf16x8*)(KB_b + (size_t)(2 * y + tile) * 4096 + mt * 1024 + ln * 16) = kv;
  } else {
    const int s = t - 512;
    const int row = s >> 3, colb = (s & 7) * 16;
    *(bf16x8*)(Gt_b + row * 128 + colb) = *(const bf16x8*)((char*)Gs + row * 144 + colb);
  }
}

// ---------------- main: zero-barrier, zero-LDS-loop flash attention ----------------
__global__ __launch_bounds__(1024, 4) void kca_attn(const char* __restrict__ KpB,
                                                    const char* __restrict__ KBB,
                                                    const char* __restrict__ GtB,
                                                    float* __restrict__ out) {
  // XCD-aware remap: each XCD gets a contiguous half-batch (L2-fit)
  const int sw_id = ((blockIdx.x & 7) << 5) | (blockIdx.x >> 3);
  const int b = sw_id >> 6, y = sw_id & 63;
  const int t = threadIdx.x;
  const int lane = t & 63, w = t >> 6;
  const int g = w & 7;           // p-group 0..7 (keys g*512 .. +512)
  const int st = w >> 3;         // q-strip 0..1 (q offset st*32)
  const int l15 = lane & 15, lg = lane >> 4;

  const char* Kp_b = KpB + (size_t)b * (HW_ * CH * 2);
  const char* KB_b = KBB + (size_t)b * (HW_ * CH * 2);
  const char* Gt_b = GtB + (size_t)b * (HW_ * CH * 2);
  float* Ob = out + (size_t)b * (CH * HW_);

  __shared__ __align__(16) char SM[69632];   // epilogue combine: 4 x [64][68] f32
  __shared__ float mll[8][64];
  __shared__ float linv[64];

  // Q fragments (wave's 32 queries, pre-scaled by log2e)
  bf16x8 qb00, qb01, qb10, qb11;
  {
    const char* qr0 = Gt_b + (size_t)(y * 64 + st * 32 + l15) * 128;
    const char* qr1 = qr0 + 16 * 128;
    qb00 = *(const bf16x8*)(qr0 + 16 * lg);
    qb01 = *(const bf16x8*)(qr0 + 64 + 16 * lg);
    qb10 = *(const bf16x8*)(qr1 + 16 * lg);
    qb11 = *(const bf16x8*)(qr1 + 64 + 16 * lg);
  }

  f32x4 oaccT[2][4];
#pragma unroll
  for (int s = 0; s < 2; ++s)
#pragma unroll
    for (int mt = 0; mt < 4; ++mt) { oaccT[s][mt][0]=0.f; oaccT[s][mt][1]=0.f; oaccT[s][mt][2]=0.f; oaccT[s][mt][3]=0.f; }
  float lpart0 = 0.f, lpart1 = 0.f;

  // loop-invariant pointers (bump by constant offsets only inside the loop)
  const int pb0 = g * 512;
  const char* arf0 = Kp_b + (size_t)(pb0 + l15) * 128 + 16 * lg;       // f=0 rows
  const char* arf1 = arf0 + 16 * 128;                                  // f=1 rows
  const char* kbp0 = KB_b + (size_t)(g * 16) * 4096 + lane * 16;

  // A-register double buffer (static names; tile i+1 loads while tile i computes)
  bf16x8 Aa0, Aa1, Aa2, Aa3, Ba0, Ba1, Ba2, Ba3;
  Aa0 = *(const bf16x8*)(arf0);        Aa1 = *(const bf16x8*)(arf0 + 64);
  Aa2 = *(const bf16x8*)(arf1);        Aa3 = *(const bf16x8*)(arf1 + 64);

#define COMPUTE(A0, A1, A2, A3, KBP)                                             \
  do {                                                                           \
    const bf16x8 kb0 = *(const bf16x8*)(KBP);                                    \
    const bf16x8 kb1 = *(const bf16x8*)((KBP) + 1024);                           \
    const bf16x8 kb2 = *(const bf16x8*)((KBP) + 2048);                           \
    const bf16x8 kb3 = *(const bf16x8*)((KBP) + 3072);                           \
    f32x4 z00 = {0.f,0.f,0.f,0.f}, z01 = {0.f,0.f,0.f,0.f};                      \
    f32x4 z10 = {0.f,0.f,0.f,0.f}, z11 = {0.f,0.f,0.f,0.f};                      \
    __builtin_amdgcn_s_setprio(1);                                               \
    z00 = __builtin_amdgcn_mfma_f32_16x16x32_bf16(A0, qb00, z00, 0, 0, 0);       \
    z00 = __builtin_amdgcn_mfma_f32_16x16x32_bf16(A1, qb01, z00, 0, 0, 0);       \
    z01 = __builtin_amdgcn_mfma_f32_16x16x32_bf16(A2, qb00, z01, 0, 0, 0);       \
    z01 = __builtin_amdgcn_mfma_f32_16x16x32_bf16(A3, qb01, z01, 0, 0, 0);       \
    z10 = __builtin_amdgcn_mfma_f32_16x16x32_bf16(A0, qb10, z10, 0, 0, 0);       \
    z10 = __builtin_amdgcn_mfma_f32_16x16x32_bf16(A1, qb11, z10, 0, 0, 0);       \
    z11 = __builtin_amdgcn_mfma_f32_16x16x32_bf16(A2, qb10, z11, 0, 0, 0);       \
    z11 = __builtin_amdgcn_mfma_f32_16x16x32_bf16(A3, qb11, z11, 0, 0, 0);       \
    __builtin_amdgcn_s_setprio(0);                                               \
    union { int wd[4]; bf16x8 v; } pa0, pa1;                                     \
    {                                                                            \
      const float e0 = exp2f(z00[0]), e1 = exp2f(z00[1]);                        \
      const float e2 = exp2f(z00[2]), e3 = exp2f(z00[3]);                        \
      const float e4 = exp2f(z01[0]), e5 = exp2f(z01[1]);                        \
      const float e6 = exp2f(z01[2]), e7 = exp2f(z01[3]);                        \
      lpart0 += ((e0 + e1) + (e2 + e3)) + ((e4 + e5) + (e6 + e7));               \
      pa0.wd[0] = pack_bf16x2(e0, e1); pa0.wd[1] = pack_bf16x2(e2, e3);          \
      pa0.wd[2] = pack_bf16x2(e4, e5); pa0.wd[3] = pack_bf16x2(e6, e7);          \
    }                                                                            \
    {                                                                            \
      const float e0 = exp2f(z10[0]), e1 = exp2f(z10[1]);                        \
      const float e2 = exp2f(z10[2]), e3 = exp2f(z10[3]);                        \
      const float e4 = exp2f(z11[0]), e5 = exp2f(z11[1]);                        \
      const float e6 = exp2f(z11[2]), e7 = exp2f(z11[3]);                        \
      lpart1 += ((e0 + e1) + (e2 + e3)) + ((e4 + e5) + (e6 + e7));               \
      pa1.wd[0] = pack_bf16x2(e0, e1); pa1.wd[1] = pack_bf16x2(e2, e3);          \
      pa1.wd[2] = pack_bf16x2(e4, e5); pa1.wd[3] = pack_bf16x2(e6, e7);          \
    }                                                                            \
    __builtin_amdgcn_s_setprio(1);                                               \
    oaccT[0][0] = __builtin_amdgcn_mfma_f32_16x16x32_bf16(pa0.v, kb0, oaccT[0][0], 0, 0, 0); \
    oaccT[1][0] = __builtin_amdgcn_mfma_f32_16x16x32_bf16(pa1.v, kb0, oaccT[1][0], 0, 0, 0); \
    oaccT[0][1] = __builtin_amdgcn_mfma_f32_16x16x32_bf16(pa0.v, kb1, oaccT[0][1], 0, 0, 0); \
    oaccT[1][1] = __builtin_amdgcn_mfma_f32_16x16x32_bf16(pa1.v, kb1, oaccT[1][1], 0, 0, 0); \
    oaccT[0][2] = __builtin_amdgcn_mfma_f32_16x16x32_bf16(pa0.v, kb2, oaccT[0][2], 0, 0, 0); \
    oaccT[1][2] = __builtin_amdgcn_mfma_f32_16x16x32_bf16(pa1.v, kb2, oaccT[1][2], 0, 0, 0); \
    oaccT[0][3] = __builtin_amdgcn_mfma_f32_16x16x32_bf16(pa0.v, kb3, oaccT[0][3], 0, 0, 0); \
    oaccT[1][3] = __builtin_amdgcn_mfma_f32_16x16x32_bf16(pa1.v, kb3, oaccT[1][3], 0, 0, 0); \
    __builtin_amdgcn_s_setprio(0);                                               \
  } while (0)

  // 16 tiles of 32 keys, 2x unrolled; prefetch next tile's A-frags into the
  // other register set before computing the current one. Final prefetch
  // over-reads into the KB region (valid ws memory, values unused).
  for (int it = 0; it < 16; it += 2) {
    const char* ar0 = arf0 + (size_t)(it + 1) * 4096;
    const char* ar1 = arf1 + (size_t)(it + 1) * 4096;
    Ba0 = *(const bf16x8*)(ar0);       Ba1 = *(const bf16x8*)(ar0 + 64);
    Ba2 = *(const bf16x8*)(ar1);       Ba3 = *(const bf16x8*)(ar1 + 64);
    COMPUTE(Aa0, Aa1, Aa2, Aa3, kbp0 + (size_t)it * 4096);

    const char* ar2 = arf0 + (size_t)(it + 2) * 4096;
    const char* ar3 = arf1 + (size_t)(it + 2) * 4096;
    Aa0 = *(const bf16x8*)(ar2);       Aa1 = *(const bf16x8*)(ar2 + 64);
    Aa2 = *(const bf16x8*)(ar3);       Aa3 = *(const bf16x8*)(ar3 + 64);
    COMPUTE(Ba0, Ba1, Ba2, Ba3, kbp0 + (size_t)(it + 1) * 4096);
  }
#undef COMPUTE

  // ---- epilogue (v6-proven): reduce l, combine 8 p-group partials, divide ----
  lpart0 += __shfl_xor(lpart0, 16); lpart0 += __shfl_xor(lpart0, 32);
  lpart1 += __shfl_xor(lpart1, 16); lpart1 += __shfl_xor(lpart1, 32);
  if (lg == 0) {
    mll[g][st * 32 + l15]      = lpart0;
    mll[g][st * 32 + 16 + l15] = lpart1;
  }
  __syncthreads();                                   // C1
  if (t < 64) {
    float L = 0.f;
#pragma unroll
    for (int k = 0; k < 8; ++k) L += mll[k][t];
    linv[t] = 1.0f / L;
  }
  float* Rg = (float*)SM + (g >> 1) * 4352;
  if ((g & 1) == 0) {
#pragma unroll
    for (int s = 0; s < 2; ++s)
#pragma unroll
      for (int mt = 0; mt < 4; ++mt)
#pragma unroll
        for (int r = 0; r < 4; ++r)
          Rg[(16 * mt + l15) * 68 + st * 32 + s * 16 + 4 * lg + r] = oaccT[s][mt][r];
  }
  __syncthreads();                                   // C2
  if (g & 1) {
#pragma unroll
    for (int s = 0; s < 2; ++s)
#pragma unroll
      for (int mt = 0; mt < 4; ++mt)
#pragma unroll
        for (int r = 0; r < 4; ++r)
          Rg[(16 * mt + l15) * 68 + st * 32 + s * 16 + 4 * lg + r] += oaccT[s][mt][r];
  }
  __syncthreads();                                   // C3
  {
    const int c = t >> 4, q4 = (t & 15) * 4;
    const float* R0 = (const float*)SM;
    f32x4 v = *(const f32x4*)(R0 + c * 68 + q4);
    v += *(const f32x4*)(R0 + 4352 + c * 68 + q4);
    v += *(const f32x4*)(R0 + 8704 + c * 68 + q4);
    v += *(const f32x4*)(R0 + 13056 + c * 68 + q4);
    const f32x4 li = *(const f32x4*)(linv + q4);
    f32x4 o;
#pragma unroll
    for (int j = 0; j < 4; ++j) o[j] = v[j] * li[j];
    *(f32x4*)(Ob + (size_t)c * HW_ + y * 64 + q4) = o;
  }
}

extern "C" void kernel_launch(void* const* d_in, const int* in_sizes, int n_in,
                              void* d_out, int out_size, void* d_ws, size_t ws_size,
                              hipStream_t stream) {
  const float* fg = (const float*)d_in[0];
  float* out = (float*)d_out;
  char* ws = (char*)d_ws;
  char* Kp = ws;                 // 2 MB  [b][p][c] bf16, linear (A-side kern)
  char* KB = ws + (2u << 20);    // 2 MB  [b][tile][mt][lane][16B] (B-side kern)
  char* Gt = ws + (4u << 20);    // 2 MB  [b][q][c] bf16 (pooled Q, log2e-prescaled)
  hipLaunchKernelGGL(kca_prep, dim3(256), dim3(1024), 0, stream, fg, Kp, KB, Gt);
  hipLaunchKernelGGL(kca_attn, dim3(256), dim3(1024), 0, stream, Kp, KB, Gt, out);
}

// Round 12
// 53.966 us; speedup vs baseline: 1.4592x; 1.4592x over previous
//
#include <hip/hip_runtime.h>

// KnowledgeConsistentAttention v11 (MI355X / gfx950)
// sumpool3x3(scores)[p,q] = kern[p,:] . G[:,q], G = sumpool3x3(fg)
// => flash attention, K=V=kern (normalized fg cols + eps), Q = G cols, d=64.
//
// v11 = v6 with ONE change: GEMM1 A-fragments read directly from L2-resident
// linear Kp (2 x 16B per lane) instead of global_load_lds staging. The main
// loop has ZERO barriers and ZERO LDS ops; transient operands only (no
// manual double-buffer -- that spilled in v10). Prep + epilogue = v6 verbatim.

typedef __bf16 bf16_t;
typedef __bf16 bf16x2 __attribute__((ext_vector_type(2)));
typedef __bf16 bf16x8 __attribute__((ext_vector_type(8)));
typedef float f32x4 __attribute__((ext_vector_type(4)));

#define HW_ 4096
#define CH 64

static __device__ __forceinline__ int pack_bf16x2(float a, float b) {
  bf16x2 p; p[0] = (bf16_t)a; p[1] = (bf16_t)b;
  return __builtin_bit_cast(int, p);
}

// ---------------- prep: kern (2 layouts) + pooled/prescaled Q ----------------
__global__ __launch_bounds__(1024, 1) void kca_prep(const float* __restrict__ fg,
                                                    char* __restrict__ KpB,
                                                    char* __restrict__ KBB,
                                                    char* __restrict__ GtB) {
  const int b = blockIdx.x >> 6, y = blockIdx.x & 63;
  const int t = threadIdx.x;
  const float* F = fg + (size_t)b * (CH * HW_);

  __shared__ float  Ft[3 * 64 * 64];   // [r][c][x] f32, rows y-1..y+1
  __shared__ bf16_t Ks[64 * 72];       // [x][c], stride 72 (144B, 16B-aligned)
  __shared__ bf16_t Gs[64 * 72];
  __shared__ float  red[16][64];
  __shared__ float  rn[64];

#pragma unroll
  for (int k = 0; k < 3; ++k) {
    const int o = t + k * 1024;          // f32x4 index
    const int r = o >> 10, c = (o >> 4) & 63, x4 = o & 15;
    const int gy = y - 1 + r;
    f32x4 v = {0.f, 0.f, 0.f, 0.f};
    if (gy >= 0 && gy <= 63) v = *(const f32x4*)(F + c * HW_ + gy * 64 + x4 * 4);
    *(f32x4*)&Ft[o * 4] = v;
  }
  __syncthreads();

  const int x = t & 63, c0 = t >> 6;     // c0 in 0..15 -> channels 4*c0..+3
  float v4[4], g4[4], ssq = 0.f;
#pragma unroll
  for (int i = 0; i < 4; ++i) {
    const int c = c0 * 4 + i;
    const float v = Ft[4096 + c * 64 + x] + 1e-7f;
    v4[i] = v; ssq = fmaf(v, v, ssq);
    float s = 0.f;
#pragma unroll
    for (int r = 0; r < 3; ++r) {
      const float* row = &Ft[r * 4096 + c * 64];
      float vv = row[x];
      if (x > 0)  vv += row[x - 1];
      if (x < 63) vv += row[x + 1];
      s += vv;
    }
    g4[i] = s * 1.4426950408889634f;     // log2e prescale (exp2-domain softmax)
  }
  red[c0][x] = ssq;
  __syncthreads();
  if (t < 512) red[t >> 6][t & 63] += red[(t >> 6) + 8][t & 63];
  __syncthreads();
  if (t < 256) red[t >> 6][t & 63] += red[(t >> 6) + 4][t & 63];
  __syncthreads();
  if (t < 64) rn[t] = 1.0f / sqrtf(red[0][t] + red[1][t] + red[2][t] + red[3][t]);
  __syncthreads();
  {
    const float rv = rn[x];
    bf16x2* ksp = (bf16x2*)((char*)Ks + x * 144 + c0 * 8);
    bf16x2* gsp = (bf16x2*)((char*)Gs + x * 144 + c0 * 8);
    bf16x2 k0; k0[0] = (bf16_t)(v4[0] * rv); k0[1] = (bf16_t)(v4[1] * rv);
    bf16x2 k1; k1[0] = (bf16_t)(v4[2] * rv); k1[1] = (bf16_t)(v4[3] * rv);
    bf16x2 g0; g0[0] = (bf16_t)g4[0]; g0[1] = (bf16_t)g4[1];
    bf16x2 g1; g1[0] = (bf16_t)g4[2]; g1[1] = (bf16_t)g4[3];
    ksp[0] = k0; ksp[1] = k1;
    gsp[0] = g0; gsp[1] = g1;
  }
  __syncthreads();

  char* Kp_b = KpB + (size_t)b * (HW_ * CH * 2) + (size_t)y * 8192;  // [p][c] 128B rows
  char* Gt_b = GtB + (size_t)b * (HW_ * CH * 2) + (size_t)y * 8192;  // [q][c] 128B rows
  char* KB_b = KBB + (size_t)b * (HW_ * CH * 2);                     // [tile][mt][lane][16B]
  if (t < 512) {
    const int row = t >> 3, colb = (t & 7) * 16;
    *(bf16x8*)(Kp_b + row * 128 + colb) = *(const bf16x8*)((char*)Ks + row * 144 + colb);
    // KB: GEMM2 B-fragment order with slot permutation baked in.
    // lane(l15,lg) word j = kern[tile*32 + 16*(j>>2) + 4*lg + (j&3)][16*mt + l15]
    const int tile = t >> 8;           // 0..1
    const int mt   = (t >> 6) & 3;
    const int ln   = t & 63;
    const int l15_ = ln & 15, lg_ = ln >> 4;
    bf16x8 kv;
#pragma unroll
    for (int j = 0; j < 8; ++j) {
      const int pl = tile * 32 + 16 * (j >> 2) + 4 * lg_ + (j & 3);
      kv[j] = Ks[pl * 72 + 16 * mt + l15_];
    }
    *(bf16x8*)(KB_b + (size_t)(2 * y + tile) * 4096 + mt * 1024 + ln * 16) = kv;
  } else {
    const int s = t - 512;
    const int row = s >> 3, colb = (s & 7) * 16;
    *(bf16x8*)(Gt_b + row * 128 + colb) = *(const bf16x8*)((char*)Gs + row * 144 + colb);
  }
}

// ---------------- main: zero-barrier, zero-loop-LDS flash attention ----------------
__global__ __launch_bounds__(1024, 4) void kca_attn(const char* __restrict__ KpB,
                                                    const char* __restrict__ KBB,
                                                    const char* __restrict__ GtB,
                                                    float* __restrict__ out) {
  // XCD-aware remap: each XCD gets a contiguous half-batch (L2-fit)
  const int sw_id = ((blockIdx.x & 7) << 5) | (blockIdx.x >> 3);
  const int b = sw_id >> 6, y = sw_id & 63;
  const int t = threadIdx.x;
  const int lane = t & 63, w = t >> 6;
  const int g = w & 7;           // p-group 0..7 (keys g*512 .. +512)
  const int st = w >> 3;         // q-strip 0..1 (q offset st*32)
  const int l15 = lane & 15, lg = lane >> 4;

  const char* Kp_b = KpB + (size_t)b * (HW_ * CH * 2);
  const char* KB_b = KBB + (size_t)b * (HW_ * CH * 2);
  const char* Gt_b = GtB + (size_t)b * (HW_ * CH * 2);
  float* Ob = out + (size_t)b * (CH * HW_);

  __shared__ __align__(16) char SM[69632];   // epilogue combine: 4 x [64][68] f32
  __shared__ float mll[8][64];
  __shared__ float linv[64];

  // Q fragments (wave's 32 queries, pre-scaled by log2e)
  bf16x8 qb00, qb01, qb10, qb11;
  {
    const char* qr0 = Gt_b + (size_t)(y * 64 + st * 32 + l15) * 128;
    const char* qr1 = qr0 + 16 * 128;
    qb00 = *(const bf16x8*)(qr0 + 16 * lg);
    qb01 = *(const bf16x8*)(qr0 + 64 + 16 * lg);
    qb10 = *(const bf16x8*)(qr1 + 16 * lg);
    qb11 = *(const bf16x8*)(qr1 + 64 + 16 * lg);
  }

  f32x4 oaccT[2][4];
#pragma unroll
  for (int s = 0; s < 2; ++s)
#pragma unroll
    for (int mt = 0; mt < 4; ++mt) { oaccT[s][mt][0]=0.f; oaccT[s][mt][1]=0.f; oaccT[s][mt][2]=0.f; oaccT[s][mt][3]=0.f; }
  float lpart0 = 0.f, lpart1 = 0.f;

  // loop-invariant bases; inner loop bumps by constant byte offsets only
  const int pb0 = g * 512;
  const char* arf = Kp_b + (size_t)(pb0 + l15) * 128 + 16 * lg;   // f=0 row of tile 0
  const char* kbp = KB_b + (size_t)(g * 16) * 4096 + lane * 16;

  for (int it = 0; it < 16; ++it) {
    // A-fragments: 2x2 direct L2 reads (16B/lane); rows f*16 apart (2048B)
    const char* ab = arf + (size_t)it * 4096;
    const bf16x8 a0 = *(const bf16x8*)(ab);
    const bf16x8 a1 = *(const bf16x8*)(ab + 64);
    const bf16x8 a2 = *(const bf16x8*)(ab + 2048);
    const bf16x8 a3 = *(const bf16x8*)(ab + 2048 + 64);
    // B-fragments for GEMM2: 4 coalesced 1KB wave-loads (L2-resident);
    // consumed only after GEMM1+exp -> latency hidden.
    const char* kb = kbp + (size_t)it * 4096;
    const bf16x8 kb0 = *(const bf16x8*)(kb);
    const bf16x8 kb1 = *(const bf16x8*)(kb + 1024);
    const bf16x8 kb2 = *(const bf16x8*)(kb + 2048);
    const bf16x8 kb3 = *(const bf16x8*)(kb + 3072);

    // ---- GEMM1: S[s][p = f*16+4lg+r][q = st*32+s*16+l15], K=64 channels ----
    f32x4 z00 = {0.f,0.f,0.f,0.f}, z01 = {0.f,0.f,0.f,0.f};
    f32x4 z10 = {0.f,0.f,0.f,0.f}, z11 = {0.f,0.f,0.f,0.f};
    z00 = __builtin_amdgcn_mfma_f32_16x16x32_bf16(a0, qb00, z00, 0, 0, 0);
    z00 = __builtin_amdgcn_mfma_f32_16x16x32_bf16(a1, qb01, z00, 0, 0, 0);
    z01 = __builtin_amdgcn_mfma_f32_16x16x32_bf16(a2, qb00, z01, 0, 0, 0);
    z01 = __builtin_amdgcn_mfma_f32_16x16x32_bf16(a3, qb01, z01, 0, 0, 0);
    z10 = __builtin_amdgcn_mfma_f32_16x16x32_bf16(a0, qb10, z10, 0, 0, 0);
    z10 = __builtin_amdgcn_mfma_f32_16x16x32_bf16(a1, qb11, z10, 0, 0, 0);
    z11 = __builtin_amdgcn_mfma_f32_16x16x32_bf16(a2, qb10, z11, 0, 0, 0);
    z11 = __builtin_amdgcn_mfma_f32_16x16x32_bf16(a3, qb11, z11, 0, 0, 0);

    // ---- fixed-bias softmax numerators: P = exp2(S) (no max needed) ----
    union { int wd[4]; bf16x8 v; } pa0, pa1;
    {
      const float e0 = exp2f(z00[0]), e1 = exp2f(z00[1]);
      const float e2 = exp2f(z00[2]), e3 = exp2f(z00[3]);
      const float e4 = exp2f(z01[0]), e5 = exp2f(z01[1]);
      const float e6 = exp2f(z01[2]), e7 = exp2f(z01[3]);
      lpart0 += ((e0 + e1) + (e2 + e3)) + ((e4 + e5) + (e6 + e7));
      pa0.wd[0] = pack_bf16x2(e0, e1); pa0.wd[1] = pack_bf16x2(e2, e3);
      pa0.wd[2] = pack_bf16x2(e4, e5); pa0.wd[3] = pack_bf16x2(e6, e7);
    }
    {
      const float e0 = exp2f(z10[0]), e1 = exp2f(z10[1]);
      const float e2 = exp2f(z10[2]), e3 = exp2f(z10[3]);
      const float e4 = exp2f(z11[0]), e5 = exp2f(z11[1]);
      const float e6 = exp2f(z11[2]), e7 = exp2f(z11[3]);
      lpart1 += ((e0 + e1) + (e2 + e3)) + ((e4 + e5) + (e6 + e7));
      pa1.wd[0] = pack_bf16x2(e0, e1); pa1.wd[1] = pack_bf16x2(e2, e3);
      pa1.wd[2] = pack_bf16x2(e4, e5); pa1.wd[3] = pack_bf16x2(e6, e7);
    }

    // ---- GEMM2 (swapped): O^T[q = 4lg+r][c = 16mt+l15] += P . kern ----
    oaccT[0][0] = __builtin_amdgcn_mfma_f32_16x16x32_bf16(pa0.v, kb0, oaccT[0][0], 0, 0, 0);
    oaccT[1][0] = __builtin_amdgcn_mfma_f32_16x16x32_bf16(pa1.v, kb0, oaccT[1][0], 0, 0, 0);
    oaccT[0][1] = __builtin_amdgcn_mfma_f32_16x16x32_bf16(pa0.v, kb1, oaccT[0][1], 0, 0, 0);
    oaccT[1][1] = __builtin_amdgcn_mfma_f32_16x16x32_bf16(pa1.v, kb1, oaccT[1][1], 0, 0, 0);
    oaccT[0][2] = __builtin_amdgcn_mfma_f32_16x16x32_bf16(pa0.v, kb2, oaccT[0][2], 0, 0, 0);
    oaccT[1][2] = __builtin_amdgcn_mfma_f32_16x16x32_bf16(pa1.v, kb2, oaccT[1][2], 0, 0, 0);
    oaccT[0][3] = __builtin_amdgcn_mfma_f32_16x16x32_bf16(pa0.v, kb3, oaccT[0][3], 0, 0, 0);
    oaccT[1][3] = __builtin_amdgcn_mfma_f32_16x16x32_bf16(pa1.v, kb3, oaccT[1][3], 0, 0, 0);
  }

  // ---- epilogue (v6-proven): reduce l, combine 8 p-group partials, divide ----
  lpart0 += __shfl_xor(lpart0, 16); lpart0 += __shfl_xor(lpart0, 32);
  lpart1 += __shfl_xor(lpart1, 16); lpart1 += __shfl_xor(lpart1, 32);
  if (lg == 0) {
    mll[g][st * 32 + l15]      = lpart0;
    mll[g][st * 32 + 16 + l15] = lpart1;
  }
  __syncthreads();                                   // C1
  if (t < 64) {
    float L = 0.f;
#pragma unroll
    for (int k = 0; k < 8; ++k) L += mll[k][t];
    linv[t] = 1.0f / L;
  }
  float* Rg = (float*)SM + (g >> 1) * 4352;
  if ((g & 1) == 0) {
#pragma unroll
    for (int s = 0; s < 2; ++s)
#pragma unroll
      for (int mt = 0; mt < 4; ++mt)
#pragma unroll
        for (int r = 0; r < 4; ++r)
          Rg[(16 * mt + l15) * 68 + st * 32 + s * 16 + 4 * lg + r] = oaccT[s][mt][r];
  }
  __syncthreads();                                   // C2
  if (g & 1) {
#pragma unroll
    for (int s = 0; s < 2; ++s)
#pragma unroll
      for (int mt = 0; mt < 4; ++mt)
#pragma unroll
        for (int r = 0; r < 4; ++r)
          Rg[(16 * mt + l15) * 68 + st * 32 + s * 16 + 4 * lg + r] += oaccT[s][mt][r];
  }
  __syncthreads();                                   // C3
  {
    const int c = t >> 4, q4 = (t & 15) * 4;
    const float* R0 = (const float*)SM;
    f32x4 v = *(const f32x4*)(R0 + c * 68 + q4);
    v += *(const f32x4*)(R0 + 4352 + c * 68 + q4);
    v += *(const f32x4*)(R0 + 8704 + c * 68 + q4);
    v += *(const f32x4*)(R0 + 13056 + c * 68 + q4);
    const f32x4 li = *(const f32x4*)(linv + q4);
    f32x4 o;
#pragma unroll
    for (int j = 0; j < 4; ++j) o[j] = v[j] * li[j];
    *(f32x4*)(Ob + (size_t)c * HW_ + y * 64 + q4) = o;
  }
}

extern "C" void kernel_launch(void* const* d_in, const int* in_sizes, int n_in,
                              void* d_out, int out_size, void* d_ws, size_t ws_size,
                              hipStream_t stream) {
  const float* fg = (const float*)d_in[0];
  float* out = (float*)d_out;
  char* ws = (char*)d_ws;
  char* Kp = ws;                 // 2 MB  [b][p][c] bf16, linear (A-side kern)
  char* KB = ws + (2u << 20);    // 2 MB  [b][tile][mt][lane][16B] (B-side kern)
  char* Gt = ws + (4u << 20);    // 2 MB  [b][q][c] bf16 (pooled Q, log2e-prescaled)
  hipLaunchKernelGGL(kca_prep, dim3(256), dim3(1024), 0, stream, fg, Kp, KB, Gt);
  hipLaunchKernelGGL(kca_attn, dim3(256), dim3(1024), 0, stream, Kp, KB, Gt, out);
}

// Round 13
// 48.275 us; speedup vs baseline: 1.6312x; 1.1179x over previous
//
#include <hip/hip_runtime.h>

// KnowledgeConsistentAttention v12 (MI355X / gfx950)
// sumpool3x3(scores)[p,q] = kern[p,:] . G[:,q], G = sumpool3x3(fg)
// => flash attention, K=V=kern (normalized fg cols + eps), Q = G cols, d=64.
//
// v12 = v6 (best measured: 44.0 us) + s_setprio(1) around the MFMA clusters
// (T5; attn-positive when waves drift between barriers). Nothing else changed:
// LDS-staged A (global_load_lds, 1 barrier/tile), direct-L2 KB B-fragments,
// fixed-bias exp2 softmax, operand-swapped zero-exchange GEMM2.

typedef __bf16 bf16_t;
typedef __bf16 bf16x2 __attribute__((ext_vector_type(2)));
typedef __bf16 bf16x8 __attribute__((ext_vector_type(8)));
typedef float f32x4 __attribute__((ext_vector_type(4)));

#define HW_ 4096
#define CH 64

static __device__ __forceinline__ void gload_lds16(const void* gsrc, void* lds_dst) {
  __builtin_amdgcn_global_load_lds(
      (const __attribute__((address_space(1))) unsigned int*)gsrc,
      (__attribute__((address_space(3))) unsigned int*)lds_dst, 16, 0, 0);
}

static __device__ __forceinline__ int pack_bf16x2(float a, float b) {
  bf16x2 p; p[0] = (bf16_t)a; p[1] = (bf16_t)b;
  return __builtin_bit_cast(int, p);
}

// ---------------- prep: kern (2 layouts) + pooled/prescaled Q ----------------
__global__ __launch_bounds__(1024, 1) void kca_prep(const float* __restrict__ fg,
                                                    char* __restrict__ KpB,
                                                    char* __restrict__ KBB,
                                                    char* __restrict__ GtB) {
  const int b = blockIdx.x >> 6, y = blockIdx.x & 63;
  const int t = threadIdx.x;
  const float* F = fg + (size_t)b * (CH * HW_);

  __shared__ float  Ft[3 * 64 * 64];   // [r][c][x] f32, rows y-1..y+1
  __shared__ bf16_t Ks[64 * 72];       // [x][c], stride 72 (144B, 16B-aligned)
  __shared__ bf16_t Gs[64 * 72];
  __shared__ float  red[16][64];
  __shared__ float  rn[64];

#pragma unroll
  for (int k = 0; k < 3; ++k) {
    const int o = t + k * 1024;          // f32x4 index
    const int r = o >> 10, c = (o >> 4) & 63, x4 = o & 15;
    const int gy = y - 1 + r;
    f32x4 v = {0.f, 0.f, 0.f, 0.f};
    if (gy >= 0 && gy <= 63) v = *(const f32x4*)(F + c * HW_ + gy * 64 + x4 * 4);
    *(f32x4*)&Ft[o * 4] = v;
  }
  __syncthreads();

  const int x = t & 63, c0 = t >> 6;     // c0 in 0..15 -> channels 4*c0..+3
  float v4[4], g4[4], ssq = 0.f;
#pragma unroll
  for (int i = 0; i < 4; ++i) {
    const int c = c0 * 4 + i;
    const float v = Ft[4096 + c * 64 + x] + 1e-7f;
    v4[i] = v; ssq = fmaf(v, v, ssq);
    float s = 0.f;
#pragma unroll
    for (int r = 0; r < 3; ++r) {
      const float* row = &Ft[r * 4096 + c * 64];
      float vv = row[x];
      if (x > 0)  vv += row[x - 1];
      if (x < 63) vv += row[x + 1];
      s += vv;
    }
    g4[i] = s * 1.4426950408889634f;     // log2e prescale (exp2-domain softmax)
  }
  red[c0][x] = ssq;
  __syncthreads();
  if (t < 512) red[t >> 6][t & 63] += red[(t >> 6) + 8][t & 63];
  __syncthreads();
  if (t < 256) red[t >> 6][t & 63] += red[(t >> 6) + 4][t & 63];
  __syncthreads();
  if (t < 64) rn[t] = 1.0f / sqrtf(red[0][t] + red[1][t] + red[2][t] + red[3][t]);
  __syncthreads();
  {
    const float rv = rn[x];
    bf16x2* ksp = (bf16x2*)((char*)Ks + x * 144 + c0 * 8);
    bf16x2* gsp = (bf16x2*)((char*)Gs + x * 144 + c0 * 8);
    bf16x2 k0; k0[0] = (bf16_t)(v4[0] * rv); k0[1] = (bf16_t)(v4[1] * rv);
    bf16x2 k1; k1[0] = (bf16_t)(v4[2] * rv); k1[1] = (bf16_t)(v4[3] * rv);
    bf16x2 g0; g0[0] = (bf16_t)g4[0]; g0[1] = (bf16_t)g4[1];
    bf16x2 g1; g1[0] = (bf16_t)g4[2]; g1[1] = (bf16_t)g4[3];
    ksp[0] = k0; ksp[1] = k1;
    gsp[0] = g0; gsp[1] = g1;
  }
  __syncthreads();

  char* Kp_b = KpB + (size_t)b * (HW_ * CH * 2) + (size_t)y * 8192;  // [p][c] 128B rows
  char* Gt_b = GtB + (size_t)b * (HW_ * CH * 2) + (size_t)y * 8192;  // [q][c] 128B rows
  char* KB_b = KBB + (size_t)b * (HW_ * CH * 2);                     // [tile][mt][lane][16B]
  if (t < 512) {
    const int row = t >> 3, colb = (t & 7) * 16;
    *(bf16x8*)(Kp_b + row * 128 + colb) = *(const bf16x8*)((char*)Ks + row * 144 + colb);
    // KB: GEMM2 B-fragment order with slot permutation baked in.
    // lane(l15,lg) word j = kern[tile*32 + 16*(j>>2) + 4*lg + (j&3)][16*mt + l15]
    const int tile = t >> 8;           // 0..1
    const int mt   = (t >> 6) & 3;
    const int ln   = t & 63;
    const int l15_ = ln & 15, lg_ = ln >> 4;
    bf16x8 kv;
#pragma unroll
    for (int j = 0; j < 8; ++j) {
      const int pl = tile * 32 + 16 * (j >> 2) + 4 * lg_ + (j & 3);
      kv[j] = Ks[pl * 72 + 16 * mt + l15_];
    }
    *(bf16x8*)(KB_b + (size_t)(2 * y + tile) * 4096 + mt * 1024 + ln * 16) = kv;
  } else {
    const int s = t - 512;
    const int row = s >> 3, colb = (s & 7) * 16;
    *(bf16x8*)(Gt_b + row * 128 + colb) = *(const bf16x8*)((char*)Gs + row * 144 + colb);
  }
}

// ---------------- main: fused flash attention ----------------
__global__ __launch_bounds__(1024, 4) void kca_attn(const char* __restrict__ KpB,
                                                    const char* __restrict__ KBB,
                                                    const char* __restrict__ GtB,
                                                    float* __restrict__ out) {
  // XCD-aware remap: each XCD gets a contiguous half-batch (L2-fit)
  const int sw_id = ((blockIdx.x & 7) << 5) | (blockIdx.x >> 3);
  const int b = sw_id >> 6, y = sw_id & 63;
  const int t = threadIdx.x;
  const int lane = t & 63, w = t >> 6;
  const int g = w & 7;           // p-group 0..7 (keys g*512 .. +512)
  const int st = w >> 3;         // q-strip 0..1 (q offset st*32)
  const int l15 = lane & 15, lg = lane >> 4;

  const char* Kp_b = KpB + (size_t)b * (HW_ * CH * 2);
  const char* KB_b = KBB + (size_t)b * (HW_ * CH * 2);
  const char* Gt_b = GtB + (size_t)b * (HW_ * CH * 2);
  float* Ob = out + (size_t)b * (CH * HW_);

  __shared__ __align__(16) char SM[69632];   // loop: Kp 8g x 2buf x 4K; combine: 4 x [64][68] f32
  __shared__ float mll[8][64];
  __shared__ float linv[64];

  char* KpG = SM + g * 8192;

  // Q fragments (wave's 32 queries, pre-scaled by log2e)
  bf16x8 qb00, qb01, qb10, qb11;
  {
    const char* qr0 = Gt_b + (size_t)(y * 64 + st * 32 + l15) * 128;
    const char* qr1 = qr0 + 16 * 128;
    qb00 = *(const bf16x8*)(qr0 + 16 * lg);
    qb01 = *(const bf16x8*)(qr0 + 64 + 16 * lg);
    qb10 = *(const bf16x8*)(qr1 + 16 * lg);
    qb11 = *(const bf16x8*)(qr1 + 64 + 16 * lg);
  }

  // staging constants (group Kp tile = 256 x 16B chunks, 2 waves x 2 chunks)
  const int cA = st * 128 + lane, cB = cA + 64;
  const int rA1 = cA >> 3, rB1 = cB >> 3;
  const size_t kpoffA = (size_t)rA1 * 128 + (((cA & 7) * 16) ^ ((rA1 & 7) << 4));
  const size_t kpoffB = (size_t)rB1 * 128 + (((cB & 7) * 16) ^ ((rB1 & 7) << 4));

#define STAGE_KP(D, P0)                                                          \
  do {                                                                           \
    gload_lds16(Kp_b + (size_t)(P0) * 128 + kpoffA, KpG + (D) * 4096 + cA * 16); \
    gload_lds16(Kp_b + (size_t)(P0) * 128 + kpoffB, KpG + (D) * 4096 + cB * 16); \
  } while (0)

  f32x4 oaccT[2][4];
#pragma unroll
  for (int s = 0; s < 2; ++s)
#pragma unroll
    for (int mt = 0; mt < 4; ++mt) { oaccT[s][mt][0]=0.f; oaccT[s][mt][1]=0.f; oaccT[s][mt][2]=0.f; oaccT[s][mt][3]=0.f; }
  float lpart0 = 0.f, lpart1 = 0.f;

  const int pb0 = g * 512;
  STAGE_KP(0, pb0);
  int cur = 0;
  for (int it = 0; it < 16; ++it) {
    __syncthreads();                       // Kp[cur] staged
    // B-fragments for this tile: 4 coalesced 1KB wave-loads, L1/L2-resident;
    // latency hides under GEMM1 + exp (compiler-inserted vmcnt before GEMM2).
    const char* kbp = KB_b + (size_t)(g * 16 + it) * 4096 + lane * 16;
    const bf16x8 kb0 = *(const bf16x8*)(kbp);
    const bf16x8 kb1 = *(const bf16x8*)(kbp + 1024);
    const bf16x8 kb2 = *(const bf16x8*)(kbp + 2048);
    const bf16x8 kb3 = *(const bf16x8*)(kbp + 3072);
    if (it + 1 < 16) STAGE_KP(cur ^ 1, pb0 + (it + 1) * 32);

    // ---- GEMM1: S[s][p = f*16+4lg+r][q = st*32+s*16+l15], K=64 channels ----
    const char* kp = KpG + cur * 4096;
    f32x4 S[2][2];
    __builtin_amdgcn_s_setprio(1);
#pragma unroll
    for (int f = 0; f < 2; ++f) {
      const int r = f * 16 + l15, swr = (r & 7) << 4;
      bf16x8 a0 = *(const bf16x8*)(kp + r * 128 + ((16 * lg) ^ swr));
      bf16x8 a1 = *(const bf16x8*)(kp + r * 128 + ((64 + 16 * lg) ^ swr));
      f32x4 z0 = {0.f, 0.f, 0.f, 0.f};
      z0 = __builtin_amdgcn_mfma_f32_16x16x32_bf16(a0, qb00, z0, 0, 0, 0);
      z0 = __builtin_amdgcn_mfma_f32_16x16x32_bf16(a1, qb01, z0, 0, 0, 0);
      S[0][f] = z0;
      f32x4 z1 = {0.f, 0.f, 0.f, 0.f};
      z1 = __builtin_amdgcn_mfma_f32_16x16x32_bf16(a0, qb10, z1, 0, 0, 0);
      z1 = __builtin_amdgcn_mfma_f32_16x16x32_bf16(a1, qb11, z1, 0, 0, 0);
      S[1][f] = z1;
    }
    __builtin_amdgcn_s_setprio(0);

    // ---- fixed-bias softmax numerators: P = exp2(S) (no max needed) ----
    // pack in k-slot order j=0..7 -> GEMM2 A-fragment, no lane exchange.
    union { int wd[4]; bf16x8 v; } pa0, pa1;
    {
      const float e0 = exp2f(S[0][0][0]), e1 = exp2f(S[0][0][1]);
      const float e2 = exp2f(S[0][0][2]), e3 = exp2f(S[0][0][3]);
      const float e4 = exp2f(S[0][1][0]), e5 = exp2f(S[0][1][1]);
      const float e6 = exp2f(S[0][1][2]), e7 = exp2f(S[0][1][3]);
      lpart0 += ((e0 + e1) + (e2 + e3)) + ((e4 + e5) + (e6 + e7));
      pa0.wd[0] = pack_bf16x2(e0, e1); pa0.wd[1] = pack_bf16x2(e2, e3);
      pa0.wd[2] = pack_bf16x2(e4, e5); pa0.wd[3] = pack_bf16x2(e6, e7);
    }
    {
      const float e0 = exp2f(S[1][0][0]), e1 = exp2f(S[1][0][1]);
      const float e2 = exp2f(S[1][0][2]), e3 = exp2f(S[1][0][3]);
      const float e4 = exp2f(S[1][1][0]), e5 = exp2f(S[1][1][1]);
      const float e6 = exp2f(S[1][1][2]), e7 = exp2f(S[1][1][3]);
      lpart1 += ((e0 + e1) + (e2 + e3)) + ((e4 + e5) + (e6 + e7));
      pa1.wd[0] = pack_bf16x2(e0, e1); pa1.wd[1] = pack_bf16x2(e2, e3);
      pa1.wd[2] = pack_bf16x2(e4, e5); pa1.wd[3] = pack_bf16x2(e6, e7);
    }

    // ---- GEMM2 (swapped): O^T[q = 4lg+r][c = 16mt+l15] += P . kern ----
    __builtin_amdgcn_s_setprio(1);
    oaccT[0][0] = __builtin_amdgcn_mfma_f32_16x16x32_bf16(pa0.v, kb0, oaccT[0][0], 0, 0, 0);
    oaccT[1][0] = __builtin_amdgcn_mfma_f32_16x16x32_bf16(pa1.v, kb0, oaccT[1][0], 0, 0, 0);
    oaccT[0][1] = __builtin_amdgcn_mfma_f32_16x16x32_bf16(pa0.v, kb1, oaccT[0][1], 0, 0, 0);
    oaccT[1][1] = __builtin_amdgcn_mfma_f32_16x16x32_bf16(pa1.v, kb1, oaccT[1][1], 0, 0, 0);
    oaccT[0][2] = __builtin_amdgcn_mfma_f32_16x16x32_bf16(pa0.v, kb2, oaccT[0][2], 0, 0, 0);
    oaccT[1][2] = __builtin_amdgcn_mfma_f32_16x16x32_bf16(pa1.v, kb2, oaccT[1][2], 0, 0, 0);
    oaccT[0][3] = __builtin_amdgcn_mfma_f32_16x16x32_bf16(pa0.v, kb3, oaccT[0][3], 0, 0, 0);
    oaccT[1][3] = __builtin_amdgcn_mfma_f32_16x16x32_bf16(pa1.v, kb3, oaccT[1][3], 0, 0, 0);
    __builtin_amdgcn_s_setprio(0);
    cur ^= 1;
  }
#undef STAGE_KP

  // ---- reduce l partials over the 4 lane-groups, publish per p-group ----
  lpart0 += __shfl_xor(lpart0, 16); lpart0 += __shfl_xor(lpart0, 32);
  lpart1 += __shfl_xor(lpart1, 16); lpart1 += __shfl_xor(lpart1, 32);
  if (lg == 0) {
    mll[g][st * 32 + l15]      = lpart0;
    mll[g][st * 32 + 16 + l15] = lpart1;
  }
  __syncthreads();                                   // C1: loop LDS dead
  if (t < 64) {
    float L = 0.f;
#pragma unroll
    for (int k = 0; k < 8; ++k) L += mll[k][t];
    linv[t] = 1.0f / L;
  }
  // combine O^T partials: 4 regions [c=64][q stride 68] f32, shared bias => plain sums
  float* Rg = (float*)SM + (g >> 1) * 4352;
  if ((g & 1) == 0) {
#pragma unroll
    for (int s = 0; s < 2; ++s)
#pragma unroll
      for (int mt = 0; mt < 4; ++mt)
#pragma unroll
        for (int r = 0; r < 4; ++r)
          Rg[(16 * mt + l15) * 68 + st * 32 + s * 16 + 4 * lg + r] = oaccT[s][mt][r];
  }
  __syncthreads();                                   // C2
  if (g & 1) {
#pragma unroll
    for (int s = 0; s < 2; ++s)
#pragma unroll
      for (int mt = 0; mt < 4; ++mt)
#pragma unroll
        for (int r = 0; r < 4; ++r)
          Rg[(16 * mt + l15) * 68 + st * 32 + s * 16 + 4 * lg + r] += oaccT[s][mt][r];
  }
  __syncthreads();                                   // C3
  {
    const int c = t >> 4, q4 = (t & 15) * 4;
    const float* R0 = (const float*)SM;
    f32x4 v = *(const f32x4*)(R0 + c * 68 + q4);
    v += *(const f32x4*)(R0 + 4352 + c * 68 + q4);
    v += *(const f32x4*)(R0 + 8704 + c * 68 + q4);
    v += *(const f32x4*)(R0 + 13056 + c * 68 + q4);
    const f32x4 li = *(const f32x4*)(linv + q4);
    f32x4 o;
#pragma unroll
    for (int j = 0; j < 4; ++j) o[j] = v[j] * li[j];
    *(f32x4*)(Ob + (size_t)c * HW_ + y * 64 + q4) = o;
  }
}

extern "C" void kernel_launch(void* const* d_in, const int* in_sizes, int n_in,
                              void* d_out, int out_size, void* d_ws, size_t ws_size,
                              hipStream_t stream) {
  const float* fg = (const float*)d_in[0];
  float* out = (float*)d_out;
  char* ws = (char*)d_ws;
  char* Kp = ws;                 // 2 MB  [b][p][c] bf16, linear (A-side kern)
  char* KB = ws + (2u << 20);    // 2 MB  [b][tile][mt][lane][16B] (B-side kern, permuted)
  char* Gt = ws + (4u << 20);    // 2 MB  [b][q][c] bf16 (pooled Q, log2e-prescaled)
  hipLaunchKernelGGL(kca_prep, dim3(256), dim3(1024), 0, stream, fg, Kp, KB, Gt);
  hipLaunchKernelGGL(kca_attn, dim3(256), dim3(1024), 0, stream, Kp, KB, Gt, out);
}